// Round 1
// baseline (231.110 us; speedup 1.0000x reference)
//
#include <hip/hip_runtime.h>
#include <hip/hip_bf16.h>

typedef short bf16x8 __attribute__((ext_vector_type(8)));
typedef float f32x4 __attribute__((ext_vector_type(4)));

#define B_ROWS 8192
#define DIM 128
#define NCLS 512
#define MMAX 64

// gamma * log2(e): logits computed in base-2 throughout
#define G2 369.32993f
#define LN2F 0.69314718056f

// ---------------- K1: L2-normalize rows; emit bf16 + fp32 copies ------------
__global__ __launch_bounds__(256) void normalize_k(const float* __restrict__ feat,
                                                   unsigned short* __restrict__ fb,
                                                   float* __restrict__ fnorm) {
    const int wv = threadIdx.x >> 6, ln = threadIdx.x & 63;
    const int row = blockIdx.x * 4 + wv;
    const float2* fr = (const float2*)(feat + row * DIM);
    float2 v = fr[ln];
    float ss = v.x * v.x + v.y * v.y;
    #pragma unroll
    for (int d = 1; d < 64; d <<= 1) ss += __shfl_xor(ss, d);
    const float inv = 1.0f / fmaxf(sqrtf(ss), 1e-12f);
    const float x = v.x * inv, y = v.y * inv;
    ((float2*)fnorm)[row * 64 + ln] = make_float2(x, y);
    __hip_bfloat16 hx = __float2bfloat16(x), hy = __float2bfloat16(y);
    unsigned int ux = *(unsigned short*)&hx, uy = *(unsigned short*)&hy;
    ((unsigned int*)fb)[row * 64 + ln] = ux | (uy << 16);
}

// ---------------- K2: per-class positives (fp32 exact) ----------------------
// Block c: find members of class c, pairwise sims, per-row lse2_p (positives)
// and lse2_same (same-class contribution to the negative-logit sum, j != i).
__global__ __launch_bounds__(128) void pos_kernel(const float* __restrict__ fnorm,
                                                  const int* __restrict__ label,
                                                  float* __restrict__ lse2_p,
                                                  float* __restrict__ lse2_same) {
    const int c = blockIdx.x;
    const int tid = threadIdx.x;
    __shared__ int rl[MMAX];
    __shared__ int s_cnt;
    __shared__ float F[MMAX][DIM + 1];
    __shared__ float SM[MMAX][MMAX];
    if (tid == 0) s_cnt = 0;
    __syncthreads();
    for (int i = tid; i < B_ROWS; i += 128) {
        if (label[i] == c) {
            int p = atomicAdd(&s_cnt, 1);
            if (p < MMAX) rl[p] = i;
        }
    }
    __syncthreads();
    const int total = s_cnt;
    const int m = total < MMAX ? total : MMAX;
    if (m == 0) return;
    const bool row_valid = (total >= 2) && (total < B_ROWS);

    for (int r = 0; r < m; ++r) F[r][tid] = fnorm[rl[r] * DIM + tid];
    __syncthreads();

    for (int p = tid; p < m * m; p += 128) {
        int i = p / m, j = p - i * m;
        float s = 0.f;
        #pragma unroll 8
        for (int k = 0; k < DIM; ++k) s = fmaf(F[i][k], F[j][k], s);
        SM[i][j] = s;
    }
    __syncthreads();

    const int wv = tid >> 6, ln = tid & 63;
    for (int i = wv; i < m; i += 2) {
        float Mp = -1e30f, Mn = -1e30f;
        for (int j = ln; j < m; j += 64) {
            if (j == i) continue;
            float s = SM[i][j];
            float up = 1.25f - s; float lp = G2 * fmaxf(up, 0.f) * (up - 0.5f);
            float un = s + 0.25f; float lnn = G2 * fmaxf(un, 0.f) * (un - 0.5f);
            Mp = fmaxf(Mp, lp); Mn = fmaxf(Mn, lnn);
        }
        #pragma unroll
        for (int d = 1; d < 64; d <<= 1) {
            Mp = fmaxf(Mp, __shfl_xor(Mp, d));
            Mn = fmaxf(Mn, __shfl_xor(Mn, d));
        }
        float Sp = 0.f, Sn = 0.f;
        for (int j = ln; j < m; j += 64) {
            if (j == i) continue;
            float s = SM[i][j];
            float up = 1.25f - s; float lp = G2 * fmaxf(up, 0.f) * (up - 0.5f);
            float un = s + 0.25f; float lnn = G2 * fmaxf(un, 0.f) * (un - 0.5f);
            Sp += __builtin_amdgcn_exp2f(lp - Mp);
            Sn += __builtin_amdgcn_exp2f(lnn - Mn);
        }
        #pragma unroll
        for (int d = 1; d < 64; d <<= 1) { Sp += __shfl_xor(Sp, d); Sn += __shfl_xor(Sn, d); }
        if (ln == 0) {
            int row = rl[i];
            lse2_p[row]    = row_valid ? (Mp + __builtin_amdgcn_logf(Sp)) : -1e30f;
            lse2_same[row] = row_valid ? (Mn + __builtin_amdgcn_logf(Sn)) : -1e30f;
        }
    }
}

// ---------------- K3: fused sim-GEMM + negative-stream online LSE -----------
// Output orientation sim^T: per lane, col(=m-row)=lane&15 fixed; acc's 4 regs
// are 4 consecutive n for that single row -> lane-local (M,S) state, group-of-4
// max trick. Fragments straight from L2-resident bf16 f (no LDS).
__global__ __launch_bounds__(256) void neg_gemm(const unsigned short* __restrict__ fb,
                                                float* __restrict__ partials) {
    const int slice = blockIdx.x & 7;
    const int mblk  = blockIdx.x >> 3;
    const int wv = threadIdx.x >> 6, ln = threadIdx.x & 63;
    const int mbase = mblk * 64 + wv * 16;
    const int lc = ln & 15, lg = ln >> 4;
    const int mrow = mbase + lc;

    const bf16x8* fv = (const bf16x8*)fb;  // 16 frags (16B) per row
    const int mb = mrow * 16 + lg;
    bf16x8 mf0 = fv[mb + 0];
    bf16x8 mf1 = fv[mb + 4];
    bf16x8 mf2 = fv[mb + 8];
    bf16x8 mf3 = fv[mb + 12];

    float M = -1e30f, S = 0.f;
    int n0 = slice * 1024;
    #pragma unroll 2
    for (int t = 0; t < 64; ++t, n0 += 16) {
        const int nb = (n0 + lc) * 16 + lg;
        bf16x8 nf0 = fv[nb + 0];
        bf16x8 nf1 = fv[nb + 4];
        bf16x8 nf2 = fv[nb + 8];
        bf16x8 nf3 = fv[nb + 12];
        f32x4 acc = {0.f, 0.f, 0.f, 0.f};
        acc = __builtin_amdgcn_mfma_f32_16x16x32_bf16(nf0, mf0, acc, 0, 0, 0);
        acc = __builtin_amdgcn_mfma_f32_16x16x32_bf16(nf1, mf1, acc, 0, 0, 0);
        acc = __builtin_amdgcn_mfma_f32_16x16x32_bf16(nf2, mf2, acc, 0, 0, 0);
        acc = __builtin_amdgcn_mfma_f32_16x16x32_bf16(nf3, mf3, acc, 0, 0, 0);

        // negative logits, base-2: l = G2 * max(s+0.25,0) * (s-0.25)
        float u0 = acc[0] + 0.25f, u1 = acc[1] + 0.25f, u2 = acc[2] + 0.25f, u3 = acc[3] + 0.25f;
        float l0 = G2 * fmaxf(u0, 0.f) * (u0 - 0.5f);
        float l1 = G2 * fmaxf(u1, 0.f) * (u1 - 0.5f);
        float l2 = G2 * fmaxf(u2, 0.f) * (u2 - 0.5f);
        float l3 = G2 * fmaxf(u3, 0.f) * (u3 - 0.5f);

        if (n0 == mbase) {  // wave-uniform: the one diagonal tile
            const int base = lg * 4;
            l0 = (base + 0 == lc) ? -3.0e8f : l0;
            l1 = (base + 1 == lc) ? -3.0e8f : l1;
            l2 = (base + 2 == lc) ? -3.0e8f : l2;
            l3 = (base + 3 == lc) ? -3.0e8f : l3;
        }

        const float gm = fmaxf(fmaxf(l0, l1), fmaxf(l2, l3));
        const float Mn = fmaxf(M, gm);
        const float r  = __builtin_amdgcn_exp2f(M - Mn);
        const float e0 = __builtin_amdgcn_exp2f(l0 - Mn);
        const float e1 = __builtin_amdgcn_exp2f(l1 - Mn);
        const float e2 = __builtin_amdgcn_exp2f(l2 - Mn);
        const float e3 = __builtin_amdgcn_exp2f(l3 - Mn);
        S = fmaf(S, r, e0) + e1 + e2 + e3;
        M = Mn;
    }

    // merge the 4 lane-group partials for each row (lanes l, l^16, l^32, l^48)
    #pragma unroll
    for (int d = 16; d < 64; d <<= 1) {
        float Mo = __shfl_xor(M, d), So = __shfl_xor(S, d);
        float Mn = fmaxf(M, Mo);
        S = S * __builtin_amdgcn_exp2f(M - Mn) + So * __builtin_amdgcn_exp2f(Mo - Mn);
        M = Mn;
    }
    if (lg == 0)
        partials[slice * B_ROWS + mbase + lc] = M + __builtin_amdgcn_logf(S);
}

// ---------------- K4: finalize ---------------------------------------------
__global__ __launch_bounds__(1024) void finalize_k(const float* __restrict__ partials,
                                                   const float* __restrict__ lse2_p,
                                                   const float* __restrict__ lse2_same,
                                                   float* __restrict__ out) {
    const int tid = threadIdx.x;
    float sum = 0.f; int cnt = 0;
    for (int r = tid; r < B_ROWS; r += 1024) {
        const float lp2 = lse2_p[r];
        if (lp2 < -1e29f) continue;  // invalid row (no positives or no negatives)
        float p[8], mx = -1e30f;
        #pragma unroll
        for (int s = 0; s < 8; ++s) { p[s] = partials[s * B_ROWS + r]; mx = fmaxf(mx, p[s]); }
        float Sa = 0.f;
        #pragma unroll
        for (int s = 0; s < 8; ++s) Sa += __builtin_amdgcn_exp2f(p[s] - mx);
        const float lse2_all = mx + __builtin_amdgcn_logf(Sa);
        // subtract same-class contribution in log space
        const float d = lse2_same[r] - lse2_all;
        const float corr = __builtin_amdgcn_logf(fmaxf(1.f - __builtin_amdgcn_exp2f(d), 1e-30f));
        const float z = LN2F * (lp2 + lse2_all + corr);
        sum += fmaxf(z, 0.f) + log1pf(expf(-fabsf(z)));  // softplus, stable
        cnt += 1;
    }
    #pragma unroll
    for (int d = 1; d < 64; d <<= 1) { sum += __shfl_xor(sum, d); cnt += __shfl_xor(cnt, d); }
    __shared__ float ssum[16];
    __shared__ int scnt[16];
    const int wv = tid >> 6;
    if ((tid & 63) == 0) { ssum[wv] = sum; scnt[wv] = cnt; }
    __syncthreads();
    if (tid == 0) {
        float ts = 0.f; int tc = 0;
        #pragma unroll
        for (int i = 0; i < 16; ++i) { ts += ssum[i]; tc += scnt[i]; }
        out[0] = ts / (float)(tc > 1 ? tc : 1);
    }
}

// ---------------- launch ----------------------------------------------------
extern "C" void kernel_launch(void* const* d_in, const int* in_sizes, int n_in,
                              void* d_out, int out_size, void* d_ws, size_t ws_size,
                              hipStream_t stream) {
    const float* feat = (const float*)d_in[0];
    const int* label = (const int*)d_in[1];
    float* out = (float*)d_out;
    char* ws = (char*)d_ws;

    unsigned short* fb = (unsigned short*)(ws);            // 2 MB bf16 normalized
    float* fnorm      = (float*)(ws + 2097152);            // 4 MB fp32 normalized
    float* partials   = (float*)(ws + 6291456);            // 8*8192*4 = 256 KB
    float* lse2_p     = (float*)(ws + 6553600);            // 32 KB
    float* lse2_same  = (float*)(ws + 6586368);            // 32 KB

    normalize_k<<<B_ROWS / 4, 256, 0, stream>>>(feat, fb, fnorm);
    pos_kernel<<<NCLS, 128, 0, stream>>>(fnorm, label, lse2_p, lse2_same);
    neg_gemm<<<1024, 256, 0, stream>>>(fb, partials);
    finalize_k<<<1, 1024, 0, stream>>>(partials, lse2_p, lse2_same, out);
}

// Round 2
// 158.981 us; speedup vs baseline: 1.4537x; 1.4537x over previous
//
#include <hip/hip_runtime.h>
#include <hip/hip_bf16.h>

typedef short bf16x8 __attribute__((ext_vector_type(8)));
typedef float f32x4 __attribute__((ext_vector_type(4)));

#define B_ROWS 8192
#define DIM 128
#define NCLS 512
#define MMAX 64
#define NSLICE 16

// gamma * log2(e): logits computed in base-2 throughout
#define G2 369.32993f
#define LN2F 0.69314718056f

// ---------------- K1: L2-normalize rows; emit bf16 + fp32 copies ------------
__global__ __launch_bounds__(256) void normalize_k(const float* __restrict__ feat,
                                                   unsigned short* __restrict__ fb,
                                                   float* __restrict__ fnorm) {
    const int wv = threadIdx.x >> 6, ln = threadIdx.x & 63;
    const int row = blockIdx.x * 4 + wv;
    const float2* fr = (const float2*)(feat + row * DIM);
    float2 v = fr[ln];
    float ss = v.x * v.x + v.y * v.y;
    #pragma unroll
    for (int d = 1; d < 64; d <<= 1) ss += __shfl_xor(ss, d);
    const float inv = 1.0f / fmaxf(sqrtf(ss), 1e-12f);
    const float x = v.x * inv, y = v.y * inv;
    ((float2*)fnorm)[row * 64 + ln] = make_float2(x, y);
    __hip_bfloat16 hx = __float2bfloat16(x), hy = __float2bfloat16(y);
    unsigned int ux = *(unsigned short*)&hx, uy = *(unsigned short*)&hy;
    ((unsigned int*)fb)[row * 64 + ln] = ux | (uy << 16);
}

// ---------------- K2a: build per-class member lists -------------------------
__global__ __launch_bounds__(256) void build_members(const int* __restrict__ label,
                                                     int* __restrict__ cls_cnt,
                                                     int* __restrict__ member) {
    const int idx = blockIdx.x * 256 + threadIdx.x;
    const int lbl = label[idx];
    const int p = atomicAdd(&cls_cnt[lbl], 1);
    if (p < MMAX) member[lbl * MMAX + p] = idx;
}

// ---------------- K2b: per-class positives (fp32 exact) ---------------------
// Block c: members of class c, fused dot + per-row lse2_p (positives) and
// lse2_same (same-class contribution to negative-logit lse, j != i).
__global__ __launch_bounds__(256) void pos_kernel(const float* __restrict__ fnorm,
                                                  const int* __restrict__ cls_cnt,
                                                  const int* __restrict__ member,
                                                  float* __restrict__ lse2_p,
                                                  float* __restrict__ lse2_same) {
    const int c = blockIdx.x;
    const int tid = threadIdx.x;
    const int total = cls_cnt[c];
    const int m = total < MMAX ? total : MMAX;
    if (m == 0) return;
    const bool row_valid = (total >= 2);

    __shared__ float F[MMAX][DIM + 1];
    __shared__ int rl[MMAX];
    for (int r = tid; r < m; r += 256) rl[r] = member[c * MMAX + r];
    __syncthreads();
    for (int idx = tid; idx < m * DIM; idx += 256) {
        const int r = idx >> 7, d = idx & 127;
        F[r][d] = fnorm[rl[r] * DIM + d];
    }
    __syncthreads();

    const int wv = tid >> 6, ln = tid & 63;
    for (int i = wv; i < m; i += 4) {
        // lane ln <-> column j; single pass: dot, logits, reduce max, reduce sum
        float s = 0.f;
        if (ln < m) {
            #pragma unroll 8
            for (int k = 0; k < DIM; ++k) s = fmaf(F[i][k], F[ln][k], s);
        }
        const bool act = (ln < m) && (ln != i);
        float up = 1.25f - s; float lp = act ? G2 * fmaxf(up, 0.f) * (up - 0.5f) : -1e30f;
        float un = s + 0.25f; float lnn = act ? G2 * fmaxf(un, 0.f) * (un - 0.5f) : -1e30f;
        float Mp = lp, Mn = lnn;
        #pragma unroll
        for (int d = 1; d < 64; d <<= 1) {
            Mp = fmaxf(Mp, __shfl_xor(Mp, d));
            Mn = fmaxf(Mn, __shfl_xor(Mn, d));
        }
        float Sp = act ? __builtin_amdgcn_exp2f(lp - Mp) : 0.f;
        float Sn = act ? __builtin_amdgcn_exp2f(lnn - Mn) : 0.f;
        #pragma unroll
        for (int d = 1; d < 64; d <<= 1) { Sp += __shfl_xor(Sp, d); Sn += __shfl_xor(Sn, d); }
        if (ln == 0) {
            const int row = rl[i];
            lse2_p[row]    = row_valid ? (Mp + __builtin_amdgcn_logf(Sp)) : -1e30f;
            lse2_same[row] = row_valid ? (Mn + __builtin_amdgcn_logf(Sn)) : -1e30f;
        }
    }
}

// ---------------- K3: fused sim-GEMM + negative-stream online LSE -----------
// 2x2 register blocking: per wave 32 m-rows x 32 n-cols per iter, 16 MFMA,
// 4 independent accumulator/LSE chains. Fragments direct from L2-resident fb.
__device__ __forceinline__ void epi4(f32x4 acc, float& M, float& S,
                                     bool diag, int lc, int lg) {
    float l0, l1, l2, l3;
    {
        float u0 = acc[0] + 0.25f; float w0 = fmaf(G2, acc[0], -0.25f * G2);
        float u1 = acc[1] + 0.25f; float w1 = fmaf(G2, acc[1], -0.25f * G2);
        float u2 = acc[2] + 0.25f; float w2 = fmaf(G2, acc[2], -0.25f * G2);
        float u3 = acc[3] + 0.25f; float w3 = fmaf(G2, acc[3], -0.25f * G2);
        l0 = fmaxf(u0, 0.f) * w0; l1 = fmaxf(u1, 0.f) * w1;
        l2 = fmaxf(u2, 0.f) * w2; l3 = fmaxf(u3, 0.f) * w3;
    }
    if (diag) {  // wave-uniform branch
        const int base = lg * 4;
        l0 = (base + 0 == lc) ? -3.0e8f : l0;
        l1 = (base + 1 == lc) ? -3.0e8f : l1;
        l2 = (base + 2 == lc) ? -3.0e8f : l2;
        l3 = (base + 3 == lc) ? -3.0e8f : l3;
    }
    const float gm = fmaxf(fmaxf(l0, l1), fmaxf(l2, l3));
    const float Mn = fmaxf(M, gm);
    const float r  = __builtin_amdgcn_exp2f(M - Mn);
    const float e0 = __builtin_amdgcn_exp2f(l0 - Mn);
    const float e1 = __builtin_amdgcn_exp2f(l1 - Mn);
    const float e2 = __builtin_amdgcn_exp2f(l2 - Mn);
    const float e3 = __builtin_amdgcn_exp2f(l3 - Mn);
    S = fmaf(S, r, e0) + e1 + e2 + e3;
    M = Mn;
}

__global__ __launch_bounds__(256, 4) void neg_gemm(const unsigned short* __restrict__ fb,
                                                   float* __restrict__ partials) {
    const int slice = blockIdx.x & (NSLICE - 1);
    const int mblk  = blockIdx.x >> 4;
    const int wv = threadIdx.x >> 6, ln = threadIdx.x & 63;
    const int lc = ln & 15, lg = ln >> 4;
    const int mb0 = mblk * 128 + wv * 32;
    const int mb1 = mb0 + 16;

    const bf16x8* fv = (const bf16x8*)fb;  // 16 frags (16B) per row
    bf16x8 a0[4], a1[4];
    #pragma unroll
    for (int k = 0; k < 4; ++k) {
        a0[k] = fv[(mb0 + lc) * 16 + lg + 4 * k];
        a1[k] = fv[(mb1 + lc) * 16 + lg + 4 * k];
    }

    float M00 = -1e30f, M01 = -1e30f, M10 = -1e30f, M11 = -1e30f;
    float S00 = 0.f, S01 = 0.f, S10 = 0.f, S11 = 0.f;

    #pragma unroll 1
    for (int t = 0; t < 16; ++t) {
        const int n0 = slice * 512 + t * 32;
        bf16x8 b0[4], b1[4];
        #pragma unroll
        for (int k = 0; k < 4; ++k) {
            b0[k] = fv[(n0 + lc) * 16 + lg + 4 * k];
            b1[k] = fv[(n0 + 16 + lc) * 16 + lg + 4 * k];
        }
        f32x4 acc00 = {0.f, 0.f, 0.f, 0.f}, acc01 = acc00, acc10 = acc00, acc11 = acc00;
        #pragma unroll
        for (int k = 0; k < 4; ++k) {
            acc00 = __builtin_amdgcn_mfma_f32_16x16x32_bf16(b0[k], a0[k], acc00, 0, 0, 0);
            acc01 = __builtin_amdgcn_mfma_f32_16x16x32_bf16(b1[k], a0[k], acc01, 0, 0, 0);
            acc10 = __builtin_amdgcn_mfma_f32_16x16x32_bf16(b0[k], a1[k], acc10, 0, 0, 0);
            acc11 = __builtin_amdgcn_mfma_f32_16x16x32_bf16(b1[k], a1[k], acc11, 0, 0, 0);
        }
        // acc[mi][ni] reg j: m-row = mb_mi + lc, n = n0 + ni*16 + lg*4 + j
        epi4(acc00, M00, S00, n0 == mb0,      lc, lg);
        epi4(acc01, M01, S01, n0 + 16 == mb0, lc, lg);
        epi4(acc10, M10, S10, n0 == mb1,      lc, lg);
        epi4(acc11, M11, S11, n0 + 16 == mb1, lc, lg);
    }

    // merge ni=0/1 chains lane-locally (same m-row)
    {
        float Mn = fmaxf(M00, M01);
        S00 = S00 * __builtin_amdgcn_exp2f(M00 - Mn) + S01 * __builtin_amdgcn_exp2f(M01 - Mn);
        M00 = Mn;
        Mn = fmaxf(M10, M11);
        S10 = S10 * __builtin_amdgcn_exp2f(M10 - Mn) + S11 * __builtin_amdgcn_exp2f(M11 - Mn);
        M10 = Mn;
    }
    // merge across lane groups (lanes l, l^16, l^32, l^48 hold disjoint n-subsets)
    #pragma unroll
    for (int d = 16; d < 64; d <<= 1) {
        float Mo = __shfl_xor(M00, d), So = __shfl_xor(S00, d);
        float Mn = fmaxf(M00, Mo);
        S00 = S00 * __builtin_amdgcn_exp2f(M00 - Mn) + So * __builtin_amdgcn_exp2f(Mo - Mn);
        M00 = Mn;
        Mo = __shfl_xor(M10, d); So = __shfl_xor(S10, d);
        Mn = fmaxf(M10, Mo);
        S10 = S10 * __builtin_amdgcn_exp2f(M10 - Mn) + So * __builtin_amdgcn_exp2f(Mo - Mn);
        M10 = Mn;
    }
    if (lg == 0) {
        partials[slice * B_ROWS + mb0 + lc] = M00 + __builtin_amdgcn_logf(S00);
        partials[slice * B_ROWS + mb1 + lc] = M10 + __builtin_amdgcn_logf(S10);
    }
}

// ---------------- K4: finalize (grid-wide, atomic accumulate) ---------------
__global__ __launch_bounds__(256) void finalize_k(const float* __restrict__ partials,
                                                  const float* __restrict__ lse2_p,
                                                  const float* __restrict__ lse2_same,
                                                  float* __restrict__ gsum,
                                                  int* __restrict__ gcnt) {
    const int r = blockIdx.x * 256 + threadIdx.x;
    float local = 0.f; int c = 0;
    const float lp2 = lse2_p[r];
    if (lp2 > -1e29f) {
        float p[NSLICE], mx = -1e30f;
        #pragma unroll
        for (int s = 0; s < NSLICE; ++s) { p[s] = partials[s * B_ROWS + r]; mx = fmaxf(mx, p[s]); }
        float Sa = 0.f;
        #pragma unroll
        for (int s = 0; s < NSLICE; ++s) Sa += __builtin_amdgcn_exp2f(p[s] - mx);
        const float lse2_all = mx + __builtin_amdgcn_logf(Sa);
        const float d = lse2_same[r] - lse2_all;
        const float corr = __builtin_amdgcn_logf(fmaxf(1.f - __builtin_amdgcn_exp2f(d), 1e-30f));
        const float z = LN2F * (lp2 + lse2_all + corr);
        local = fmaxf(z, 0.f) + log1pf(expf(-fabsf(z)));  // stable softplus
        c = 1;
    }
    const int ln = threadIdx.x & 63;
    #pragma unroll
    for (int d = 1; d < 64; d <<= 1) { local += __shfl_xor(local, d); c += __shfl_xor(c, d); }
    if (ln == 0) { atomicAdd(gsum, local); atomicAdd(gcnt, c); }
}

__global__ void div_kernel(const float* __restrict__ gsum, const int* __restrict__ gcnt,
                           float* __restrict__ out) {
    const int n = gcnt[0];
    out[0] = gsum[0] / (float)(n > 1 ? n : 1);
}

// ---------------- launch ----------------------------------------------------
extern "C" void kernel_launch(void* const* d_in, const int* in_sizes, int n_in,
                              void* d_out, int out_size, void* d_ws, size_t ws_size,
                              hipStream_t stream) {
    const float* feat = (const float*)d_in[0];
    const int* label = (const int*)d_in[1];
    float* out = (float*)d_out;
    char* ws = (char*)d_ws;

    unsigned short* fb = (unsigned short*)(ws);             // 2 MB bf16 normalized
    float* fnorm      = (float*)(ws + (2 << 20));           // 4 MB fp32 normalized
    float* partials   = (float*)(ws + (6 << 20));           // 16*8192*4 = 512 KB
    float* lse2_p     = (float*)(ws + (6 << 20) + 524288);  // 32 KB
    float* lse2_same  = (float*)(ws + (6 << 20) + 557056);  // 32 KB
    int*   cls_cnt    = (int*)  (ws + (6 << 20) + 589824);  // 2 KB
    int*   member     = (int*)  (ws + (6 << 20) + 591872);  // 128 KB
    float* gsum       = (float*)(ws + (6 << 20) + 722944);  // 4 B
    int*   gcnt       = (int*)  (ws + (6 << 20) + 722948);  // 4 B

    hipMemsetAsync(cls_cnt, 0, NCLS * sizeof(int), stream);
    hipMemsetAsync(gsum, 0, 8, stream);

    normalize_k<<<B_ROWS / 4, 256, 0, stream>>>(feat, fb, fnorm);
    build_members<<<B_ROWS / 256, 256, 0, stream>>>(label, cls_cnt, member);
    pos_kernel<<<NCLS, 256, 0, stream>>>(fnorm, cls_cnt, member, lse2_p, lse2_same);
    neg_gemm<<<64 * NSLICE, 256, 0, stream>>>(fb, partials);
    finalize_k<<<B_ROWS / 256, 256, 0, stream>>>(partials, lse2_p, lse2_same, gsum, gcnt);
    div_kernel<<<1, 1, 0, stream>>>(gsum, gcnt, out);
}

// Round 3
// 122.612 us; speedup vs baseline: 1.8849x; 1.2966x over previous
//
#include <hip/hip_runtime.h>
#include <hip/hip_bf16.h>

typedef short bf16x8 __attribute__((ext_vector_type(8)));
typedef float f32x4 __attribute__((ext_vector_type(4)));

#define B_ROWS 8192
#define DIM 128
#define NCLS 512
#define MMAX 64
#define NSLICE 32
#define NEG_BLOCKS 1024

// gamma * log2(e): logits computed in base-2 throughout
#define G2 369.32993f
#define LN2F 0.69314718056f

// ---------------- K1: normalize rows (bf16+fp32 out) + build member lists ---
__global__ __launch_bounds__(256) void prep_k(const float* __restrict__ feat,
                                              const int* __restrict__ label,
                                              unsigned short* __restrict__ fb,
                                              float* __restrict__ fnorm,
                                              int* __restrict__ cls_cnt,
                                              int* __restrict__ member) {
    const int wv = threadIdx.x >> 6, ln = threadIdx.x & 63;
    const int row = blockIdx.x * 4 + wv;
    const float2* fr = (const float2*)(feat + row * DIM);
    float2 v = fr[ln];
    float ss = v.x * v.x + v.y * v.y;
    #pragma unroll
    for (int d = 1; d < 64; d <<= 1) ss += __shfl_xor(ss, d);
    const float inv = 1.0f / fmaxf(sqrtf(ss), 1e-12f);
    const float x = v.x * inv, y = v.y * inv;
    ((float2*)fnorm)[row * 64 + ln] = make_float2(x, y);
    __hip_bfloat16 hx = __float2bfloat16(x), hy = __float2bfloat16(y);
    unsigned int ux = *(unsigned short*)&hx, uy = *(unsigned short*)&hy;
    ((unsigned int*)fb)[row * 64 + ln] = ux | (uy << 16);

    // member-list build: first 32 blocks cover all 8192 labels
    if (blockIdx.x < 32) {
        const int idx = blockIdx.x * 256 + threadIdx.x;
        const int lbl = label[idx];
        const int p = atomicAdd(&cls_cnt[lbl], 1);
        if (p < MMAX) member[lbl * MMAX + p] = idx;
    }
}

// ---------------- epilogue for one f32x4 acc --------------------------------
__device__ __forceinline__ void epi4(f32x4 acc, float& M, float& S,
                                     bool diag, int lc, int lg) {
    float u0 = acc[0] + 0.25f; float w0 = fmaf(G2, acc[0], -0.25f * G2);
    float u1 = acc[1] + 0.25f; float w1 = fmaf(G2, acc[1], -0.25f * G2);
    float u2 = acc[2] + 0.25f; float w2 = fmaf(G2, acc[2], -0.25f * G2);
    float u3 = acc[3] + 0.25f; float w3 = fmaf(G2, acc[3], -0.25f * G2);
    float l0 = fmaxf(u0, 0.f) * w0, l1 = fmaxf(u1, 0.f) * w1;
    float l2 = fmaxf(u2, 0.f) * w2, l3 = fmaxf(u3, 0.f) * w3;
    if (diag) {  // wave-uniform: the one diagonal tile
        const int base = lg * 4;
        l0 = (base + 0 == lc) ? -3.0e8f : l0;
        l1 = (base + 1 == lc) ? -3.0e8f : l1;
        l2 = (base + 2 == lc) ? -3.0e8f : l2;
        l3 = (base + 3 == lc) ? -3.0e8f : l3;
    }
    const float gm = fmaxf(fmaxf(l0, l1), fmaxf(l2, l3));
    // skip tiles that can't contribute > 2^-25 relative (wave-coherent)
    if (__any(gm > M - 25.f)) {
        const float Mn = fmaxf(M, gm);
        const float r  = __builtin_amdgcn_exp2f(M - Mn);
        const float e0 = __builtin_amdgcn_exp2f(l0 - Mn);
        const float e1 = __builtin_amdgcn_exp2f(l1 - Mn);
        const float e2 = __builtin_amdgcn_exp2f(l2 - Mn);
        const float e3 = __builtin_amdgcn_exp2f(l3 - Mn);
        S = fmaf(S, r, e0) + e1 + e2 + e3;
        M = Mn;
    }
}

// ---------------- K2: fused neg-GEMM-LSE (blocks 0..1023) + positives -------
__global__ __launch_bounds__(256) void main_k(const unsigned short* __restrict__ fb,
                                              const float* __restrict__ fnorm,
                                              const int* __restrict__ cls_cnt,
                                              const int* __restrict__ member,
                                              float* __restrict__ partials,
                                              float* __restrict__ lse2_p,
                                              float* __restrict__ lse2_same) {
    __shared__ float F[MMAX][DIM + 1];
    __shared__ int rl[MMAX];
    const int bid = blockIdx.x;

    if (bid < NEG_BLOCKS) {
        // ---- negative stream: 4x1 blocking, 64 m-rows x 16 n per iter ----
        const int slice = bid & 31;        // n-range: slice*256 .. +256
        const int mblk  = bid >> 5;       // m-range: mblk*256 .. +256
        const int wv = threadIdx.x >> 6, ln = threadIdx.x & 63;
        const int lc = ln & 15, lg = ln >> 4;
        const int mb = mblk * 256 + wv * 64;
        const bf16x8* fv = (const bf16x8*)fb;  // 16 frags (16B) per row

        bf16x8 a[4][4];
        #pragma unroll
        for (int mi = 0; mi < 4; ++mi)
            #pragma unroll
            for (int k = 0; k < 4; ++k)
                a[mi][k] = fv[(mb + mi * 16 + lc) * 16 + lg + 4 * k];

        float M[4], S[4];
        #pragma unroll
        for (int mi = 0; mi < 4; ++mi) { M[mi] = -1e30f; S[mi] = 0.f; }

        const int nbase = slice * 256;
        bf16x8 bA[4], bB[4];

        #define LOADB(dst, n0) { \
            _Pragma("unroll") \
            for (int k = 0; k < 4; ++k) dst[k] = fv[((n0) + lc) * 16 + lg + 4 * k]; }

        #define STEP(bR, n0) { \
            f32x4 acc[4]; \
            _Pragma("unroll") \
            for (int mi = 0; mi < 4; ++mi) acc[mi] = (f32x4){0.f, 0.f, 0.f, 0.f}; \
            _Pragma("unroll") \
            for (int k = 0; k < 4; ++k) { \
                _Pragma("unroll") \
                for (int mi = 0; mi < 4; ++mi) \
                    acc[mi] = __builtin_amdgcn_mfma_f32_16x16x32_bf16(bR[k], a[mi][k], acc[mi], 0, 0, 0); \
            } \
            _Pragma("unroll") \
            for (int mi = 0; mi < 4; ++mi) \
                epi4(acc[mi], M[mi], S[mi], (n0) == mb + mi * 16, lc, lg); }

        LOADB(bA, nbase);
        #pragma unroll 1
        for (int t = 0; t < 16; t += 2) {
            LOADB(bB, nbase + (t + 1) * 16);
            STEP(bA, nbase + t * 16);
            if (t + 2 < 16) LOADB(bA, nbase + (t + 2) * 16);
            STEP(bB, nbase + (t + 1) * 16);
        }
        #undef LOADB
        #undef STEP

        // merge across lane groups (lanes l, l^16, l^32, l^48: disjoint n-subsets)
        #pragma unroll
        for (int mi = 0; mi < 4; ++mi) {
            float Mm = M[mi], Ss = S[mi];
            #pragma unroll
            for (int d = 16; d < 64; d <<= 1) {
                float Mo = __shfl_xor(Mm, d), So = __shfl_xor(Ss, d);
                float Mn = fmaxf(Mm, Mo);
                Ss = Ss * __builtin_amdgcn_exp2f(Mm - Mn) + So * __builtin_amdgcn_exp2f(Mo - Mn);
                Mm = Mn;
            }
            if (lg == 0)
                partials[slice * B_ROWS + mb + mi * 16 + lc] = Mm + __builtin_amdgcn_logf(Ss);
        }
    } else {
        // ---- positives: per-class exact fp32 (class c = bid - NEG_BLOCKS) ----
        const int c = bid - NEG_BLOCKS;
        const int tid = threadIdx.x;
        const int total = cls_cnt[c];
        const int m = total < MMAX ? total : MMAX;
        if (m == 0) return;
        const bool row_valid = (total >= 2);

        for (int r = tid; r < m; r += 256) rl[r] = member[c * MMAX + r];
        __syncthreads();
        for (int idx = tid; idx < m * DIM; idx += 256) {
            const int r = idx >> 7, d = idx & 127;
            F[r][d] = fnorm[rl[r] * DIM + d];
        }
        __syncthreads();

        const int wv = tid >> 6, ln = tid & 63;
        for (int i = wv; i < m; i += 4) {
            float s = 0.f;
            if (ln < m) {
                #pragma unroll 8
                for (int k = 0; k < DIM; ++k) s = fmaf(F[i][k], F[ln][k], s);
            }
            const bool act = (ln < m) && (ln != i);
            float up = 1.25f - s; float lp = act ? G2 * fmaxf(up, 0.f) * (up - 0.5f) : -1e30f;
            float un = s + 0.25f; float lnn = act ? G2 * fmaxf(un, 0.f) * (un - 0.5f) : -1e30f;
            float Mp = lp, Mn = lnn;
            #pragma unroll
            for (int d = 1; d < 64; d <<= 1) {
                Mp = fmaxf(Mp, __shfl_xor(Mp, d));
                Mn = fmaxf(Mn, __shfl_xor(Mn, d));
            }
            float Sp = act ? __builtin_amdgcn_exp2f(lp - Mp) : 0.f;
            float Sn = act ? __builtin_amdgcn_exp2f(lnn - Mn) : 0.f;
            #pragma unroll
            for (int d = 1; d < 64; d <<= 1) { Sp += __shfl_xor(Sp, d); Sn += __shfl_xor(Sn, d); }
            if (ln == 0) {
                const int row = rl[i];
                lse2_p[row]    = row_valid ? (Mp + __builtin_amdgcn_logf(Sp)) : -1e30f;
                lse2_same[row] = row_valid ? (Mn + __builtin_amdgcn_logf(Sn)) : -1e30f;
            }
        }
    }
}

// ---------------- K3: finalize, last block writes out -----------------------
__global__ __launch_bounds__(256) void finalize_k(const float* __restrict__ partials,
                                                  const float* __restrict__ lse2_p,
                                                  const float* __restrict__ lse2_same,
                                                  float* __restrict__ gsum,
                                                  int* __restrict__ gcnt,
                                                  int* __restrict__ done,
                                                  float* __restrict__ out) {
    const int r = blockIdx.x * 256 + threadIdx.x;
    float local = 0.f; int c = 0;
    const float lp2 = lse2_p[r];
    if (lp2 > -1e29f) {
        float p[NSLICE], mx = -1e30f;
        #pragma unroll
        for (int s = 0; s < NSLICE; ++s) { p[s] = partials[s * B_ROWS + r]; mx = fmaxf(mx, p[s]); }
        float Sa = 0.f;
        #pragma unroll
        for (int s = 0; s < NSLICE; ++s) Sa += __builtin_amdgcn_exp2f(p[s] - mx);
        const float lse2_all = mx + __builtin_amdgcn_logf(Sa);
        const float d = lse2_same[r] - lse2_all;
        const float corr = __builtin_amdgcn_logf(fmaxf(1.f - __builtin_amdgcn_exp2f(d), 1e-30f));
        const float z = LN2F * (lp2 + lse2_all + corr);
        local = fmaxf(z, 0.f) + log1pf(expf(-fabsf(z)));  // stable softplus
        c = 1;
    }
    #pragma unroll
    for (int d = 1; d < 64; d <<= 1) { local += __shfl_xor(local, d); c += __shfl_xor(c, d); }
    __shared__ float wsum[4];
    __shared__ int wcnt[4];
    const int wv = threadIdx.x >> 6;
    if ((threadIdx.x & 63) == 0) { wsum[wv] = local; wcnt[wv] = c; }
    __syncthreads();
    if (threadIdx.x == 0) {
        const float ts = wsum[0] + wsum[1] + wsum[2] + wsum[3];
        const int tc = wcnt[0] + wcnt[1] + wcnt[2] + wcnt[3];
        atomicAdd(gsum, ts);
        atomicAdd(gcnt, tc);
        __threadfence();
        const int ticket = atomicAdd(done, 1);
        if (ticket == (int)gridDim.x - 1) {
            const float gs = atomicAdd(gsum, 0.0f);  // coherent read-after-all
            const int gc = atomicAdd(gcnt, 0);
            out[0] = gs / (float)(gc > 1 ? gc : 1);
        }
    }
}

// ---------------- launch ----------------------------------------------------
extern "C" void kernel_launch(void* const* d_in, const int* in_sizes, int n_in,
                              void* d_out, int out_size, void* d_ws, size_t ws_size,
                              hipStream_t stream) {
    const float* feat = (const float*)d_in[0];
    const int* label = (const int*)d_in[1];
    float* out = (float*)d_out;
    char* ws = (char*)d_ws;

    unsigned short* fb = (unsigned short*)(ws);                 // 2 MB bf16 normalized
    float* fnorm      = (float*)(ws + (2u << 20));              // 4 MB fp32 normalized
    float* partials   = (float*)(ws + (6u << 20));              // 32*8192*4 = 1 MB
    char*  tail       = ws + (7u << 20);
    float* lse2_p     = (float*)(tail);                         // 32 KB
    float* lse2_same  = (float*)(tail + 32768);                 // 32 KB
    int*   member     = (int*)  (tail + 65536);                 // 128 KB
    int*   cls_cnt    = (int*)  (tail + 196608);                // 2048 B
    float* gsum       = (float*)(tail + 198656);                // 4 B
    int*   gcnt       = (int*)  (tail + 198660);                // 4 B
    int*   done       = (int*)  (tail + 198664);                // 4 B

    // single control memset: cls_cnt + gsum + gcnt + done (contiguous)
    hipMemsetAsync(cls_cnt, 0, 2048 + 12, stream);

    prep_k<<<B_ROWS / 4, 256, 0, stream>>>(feat, label, fb, fnorm, cls_cnt, member);
    main_k<<<NEG_BLOCKS + NCLS, 256, 0, stream>>>(fb, fnorm, cls_cnt, member,
                                                  partials, lse2_p, lse2_same);
    finalize_k<<<B_ROWS / 256, 256, 0, stream>>>(partials, lse2_p, lse2_same,
                                                 gsum, gcnt, done, out);
}